// Round 2
// baseline (159.823 us; speedup 1.0000x reference)
//
#include <hip/hip_runtime.h>

#define T_LEN 120000
#define LBLK 160          // samples per scan block
#define HBLK 80           // half block: pass3 workgroup granularity
#define PBLK 750          // logical blocks over T (time geometry)
#define PB_USED 500       // blocks pass1 computes (only 0..499 are consumed)
#define SEG_LEN 25        // blocks per scan segment
#define NSEG_USED 20      // segment aggregates needed (blocks 0..499)
#define SEGC0 10          // first segment expanded to per-block states
#define NSEGC 11          // segments 10..20 expanded by pass2c
#define CCH 16            // t-steps per recurrence wave per chunk
#define NCHUNK 5          // chunks per half block (5*16 = 80)
#define BATCH 4
#define K0 250            // first valid block (t = 40000)
#define NKV 250           // valid blocks (t in [40000, 80000))
#define DENOM 20480000.0  // 2 * 4 * 64 * 40000 (each |diff| counted twice)
#define YSTR 130          // halves per ys row: 128 ch + 2 pad (odd dword stride)

typedef _Float16 half8 __attribute__((ext_vector_type(8)));
typedef float f32x4 __attribute__((ext_vector_type(4)));

__device__ __forceinline__ float fast_tanh(float x) {
  float e = __expf(2.0f * x);
  return 1.0f - 2.0f / (e + 1.0f);
}

// Harness may store the reference's float64 coeff arrays as f64 or f32.
// Detect via a2[0] = r^2 in (0.9,1.0). Data-stable -> graph-safe; no OOB.
__device__ __forceinline__ bool coeffs_are_f64(const void* a2p) {
  double probe = *(const double*)a2p;
  return probe > 0.9 && probe < 1.0;
}
__device__ __forceinline__ double coeff_d(const void* p, bool f64, int ch) {
  return f64 ? ((const double*)p)[ch] : (double)((const float*)p)[ch];
}

// state-transition matrix A^e for A = [[-a1,-a2],[1,0]] by repeated squaring
__device__ __forceinline__ void mat_pow(double A1, double A2, int e,
                                        double& r00, double& r01,
                                        double& r10, double& r11) {
  double m00 = -A1, m01 = -A2, m10 = 1.0, m11 = 0.0;
  r00 = 1.0; r01 = 0.0; r10 = 0.0; r11 = 1.0;
  while (e) {
    if (e & 1) {
      double t00 = r00 * m00 + r01 * m10, t01 = r00 * m01 + r01 * m11;
      double t10 = r10 * m00 + r11 * m10, t11 = r10 * m01 + r11 * m11;
      r00 = t00; r01 = t01; r10 = t10; r11 = t11;
    }
    e >>= 1;
    if (e) {
      double t00 = m00 * m00 + m01 * m10, t01 = m00 * m01 + m01 * m11;
      double t10 = m10 * m00 + m11 * m10, t11 = m10 * m01 + m11 * m11;
      m00 = t00; m01 = t01; m10 = t10; m11 = t11;
    }
  }
}

// Pass 1: per (row, block) forced response with zero initial state, f32.
// rows r: r = i*8 + d*4 + b. Also captures the half-block (j==80) state for
// blocks [K0, K0+NKV) -> fmid, and zeroes wsum/counter (block 0 only).
__global__ __launch_bounds__(64) void pass1(
    const float* __restrict__ pred, const float* __restrict__ tgt,
    const void* a1p, const void* a2p, const void* b0p,
    double* __restrict__ fbuf, double* __restrict__ fmid,
    double* __restrict__ wsum)
{
  if ((blockIdx.x | blockIdx.y) == 0 && threadIdx.x == 0) {
    wsum[0] = 0.0;
    ((unsigned int*)(wsum + 1))[0] = 0u;   // workgroup-done counter
  }
  int k = blockIdx.x, r = blockIdx.y;
  int i = r >> 3, d = (r >> 2) & 1, b = r & 3;
  const float* sig = (i ? tgt : pred) + b * T_LEN;
  __shared__ float xs[LBLK];
  int base = k * LBLK;
  for (int j = threadIdx.x; j < LBLK; j += 64)
    xs[j] = d ? sig[T_LEN - 1 - (base + j)] : sig[base + j];
  __syncthreads();
  int ch = threadIdx.x;
  bool f64 = coeffs_are_f64(a2p);
  float A1 = (float)coeff_d(a1p, f64, ch);
  float A2 = (float)coeff_d(a2p, f64, ch);
  float B0 = (float)coeff_d(b0p, f64, ch);
  float y1 = 0.0f, y2 = 0.0f;
  for (int j = 0; j < HBLK; ++j) {
    float y = fmaf(-A1, y1, fmaf(-A2, y2, B0 * xs[j]));
    y2 = y1; y1 = y;
  }
  int s = r * 64 + ch;
  if (k >= K0 && k < K0 + NKV)
    ((double2*)fmid)[(size_t)(k - K0) * 1024 + s] =
        make_double2((double)y1, (double)y2);
  for (int j = HBLK; j < LBLK; ++j) {
    float y = fmaf(-A1, y1, fmaf(-A2, y2, B0 * xs[j]));
    y2 = y1; y1 = y;
  }
  ((double2*)fbuf)[(size_t)k * 1024 + s] = make_double2((double)y1, (double)y2);
}

// Pass 2a: per-segment aggregate (forced response of 25 blocks, zero init), f64.
__global__ __launch_bounds__(64) void pass2a(
    const void* a1p, const void* a2p,
    const double* __restrict__ fbuf, double* __restrict__ sbuf)
{
  int seg = blockIdx.x >> 4;
  int s = ((blockIdx.x & 15) << 6) + threadIdx.x;
  int ch = s & 63;
  bool f64 = coeffs_are_f64(a2p);
  double r00, r01, r10, r11;
  mat_pow(coeff_d(a1p, f64, ch), coeff_d(a2p, f64, ch), LBLK, r00, r01, r10, r11);
  const double2* fb = (const double2*)fbuf;
  double y1 = 0.0, y2 = 0.0;
  for (int jj = 0; jj < SEG_LEN / 5; ++jj) {
    size_t kb = (size_t)(seg * SEG_LEN + jj * 5) * 1024 + s;
    double2 f0 = fb[kb], f1 = fb[kb + 1024], f2 = fb[kb + 2048],
            f3 = fb[kb + 3072], f4 = fb[kb + 4096];
    double n1, n2;
    n1 = r00*y1 + r01*y2 + f0.x; n2 = r10*y1 + r11*y2 + f0.y; y1=n1; y2=n2;
    n1 = r00*y1 + r01*y2 + f1.x; n2 = r10*y1 + r11*y2 + f1.y; y1=n1; y2=n2;
    n1 = r00*y1 + r01*y2 + f2.x; n2 = r10*y1 + r11*y2 + f2.y; y1=n1; y2=n2;
    n1 = r00*y1 + r01*y2 + f3.x; n2 = r10*y1 + r11*y2 + f3.y; y1=n1; y2=n2;
    n1 = r00*y1 + r01*y2 + f4.x; n2 = r10*y1 + r11*y2 + f4.y; y1=n1; y2=n2;
  }
  ((double2*)sbuf)[(size_t)seg * 1024 + s] = make_double2(y1, y2);
}

// Pass 2b: serial scan over 20 segment aggregates -> segment-start states
// tbuf[0..20]. All loads prefetched (state-independent).
__global__ __launch_bounds__(256) void pass2b(
    const void* a1p, const void* a2p,
    const double* __restrict__ sbuf, double* __restrict__ tbuf)
{
  int s = blockIdx.x * 256 + threadIdx.x;
  int ch = s & 63;
  bool f64 = coeffs_are_f64(a2p);
  double r00, r01, r10, r11;
  mat_pow(coeff_d(a1p, f64, ch), coeff_d(a2p, f64, ch), LBLK * SEG_LEN,
          r00, r01, r10, r11);
  const double2* sb = (const double2*)sbuf;
  double2* tb = (double2*)tbuf;
  double y1 = 0.0, y2 = 0.0;
  #pragma unroll 1
  for (int half = 0; half < 2; ++half) {
    int bse = half * 10;
    double2 f[10];
    #pragma unroll
    for (int q = 0; q < 10; ++q) f[q] = sb[(size_t)(bse + q) * 1024 + s];
    #pragma unroll
    for (int q = 0; q < 10; ++q) {
      tb[(size_t)(bse + q) * 1024 + s] = make_double2(y1, y2);
      double n1 = r00 * y1 + r01 * y2 + f[q].x;
      double n2 = r10 * y1 + r11 * y2 + f[q].y;
      y1 = n1; y2 = n2;
    }
  }
  tb[(size_t)NSEG_USED * 1024 + s] = make_double2(y1, y2);
}

// Pass 2c: expand segment-start states into exact f64 per-(block,half) start
// states for blocks [K0, K0+250]: stbuf[m-K0][0] = block-start state,
// stbuf[m-K0][1] = mid-block state = A^80 * start + fmid[m]. This replaces
// pass3's per-wave f64 prologue (mat_pow + predicated scan + fbuf loads).
__global__ __launch_bounds__(64) void pass2c(
    const void* a1p, const void* a2p,
    const double* __restrict__ fbuf, const double* __restrict__ fmid,
    const double* __restrict__ tbuf, double* __restrict__ stbuf)
{
  int seg = SEGC0 + (blockIdx.x >> 4);
  int s = ((blockIdx.x & 15) << 6) + threadIdx.x;
  int ch = s & 63;
  bool f64 = coeffs_are_f64(a2p);
  double A1d = coeff_d(a1p, f64, ch), A2d = coeff_d(a2p, f64, ch);
  double p00, p01, p10, p11;
  mat_pow(A1d, A2d, HBLK, p00, p01, p10, p11);      // A^80
  double r00 = p00*p00 + p01*p10, r01 = p00*p01 + p01*p11;  // A^160
  double r10 = p10*p00 + p11*p10, r11 = p10*p01 + p11*p11;
  double2 v0 = ((const double2*)tbuf)[(size_t)seg * 1024 + s];
  double y1 = v0.x, y2 = v0.y;
  const double2* fb = (const double2*)fbuf;
  const double2* fm = (const double2*)fmid;
  double2* st = (double2*)stbuf;
  #pragma unroll 1
  for (int jb = 0; jb < SEG_LEN; jb += 5) {
    double2 fv[5], fmv[5];
    #pragma unroll
    for (int q = 0; q < 5; ++q) {
      int m = seg * SEG_LEN + jb + q;
      int mc = m < PB_USED ? m : PB_USED - 1;       // clamp (values unused OOB)
      fv[q]  = fb[(size_t)mc * 1024 + s];
      fmv[q] = fm[(size_t)(mc - K0) * 1024 + s];
    }
    #pragma unroll
    for (int q = 0; q < 5; ++q) {
      int m = seg * SEG_LEN + jb + q;
      if (m <= K0 + NKV) {                          // m in [250, 500]
        int mi = m - K0;
        st[(size_t)(mi * 2) * 1024 + s] = make_double2(y1, y2);
        if (m < K0 + NKV) {
          st[(size_t)(mi * 2 + 1) * 1024 + s] =
              make_double2(p00 * y1 + p01 * y2 + fmv[q].x,
                           p10 * y1 + p11 * y2 + fmv[q].y);
          double n1 = r00 * y1 + r01 * y2 + fv[q].x;
          double n2 = r10 * y1 + r11 * y2 + fv[q].y;
          y1 = n1; y2 = n2;
        }
      }
    }
  }
}

// Pass 3: per (valid block k, half h, batch b). 256 threads = 4 waves
// (2 inputs x 2 dirs). Each wave: one 16B stbuf load (exact f64 start state),
// 80 f32 recurrence steps in 5 chunks of 16 -> f16 Y in LDS (double-buffered)
// -> MFMA 16x16x32_f16 (wave owns row-tile gu, iterates 2 col-tiles) -> tanh
// -> |p-t|. VGPR-capped at 64 (8 WGs/CU, whole 2000-WG grid co-resident).
// Finalize fused via atomic counter (last workgroup writes out).
__global__ __launch_bounds__(256, 8) void pass3(
    const float* __restrict__ pred, const float* __restrict__ tgt,
    const void* a1p, const void* a2p, const void* b0p,
    const float* __restrict__ W, const double* __restrict__ stbuf,
    double* __restrict__ wsum, float* __restrict__ out)
{
  int kx = blockIdx.x;
  int k = K0 + (kx >> 1), hu = kx & 1;   // block, half (both wg-uniform)
  int b = blockIdx.y;
  int tid = threadIdx.x;
  __shared__ __align__(16) _Float16 ys[2][32 * YSTR]; // [buf][col(2t+i)][128ch]
  __shared__ float red[4];

  int g = tid >> 6, lane = tid & 63;
  int gu = __builtin_amdgcn_readfirstlane(g);   // wave-uniform wave id
  int iu = gu & 1, du = gu >> 1;                // input / direction
  int ch = lane;
  int lm = lane & 15, quad = lane >> 4;

  bool f64 = coeffs_are_f64(a2p);
  double A1d = coeff_d(a1p, f64, ch), A2d = coeff_d(a2p, f64, ch);
  double B0d = coeff_d(b0p, f64, ch);
  float A1 = (float)A1d, A2 = (float)A2d, B0 = (float)B0d;
  float IA2 = (float)(1.0 / A2d);

  // exact f64 start state for this wave's half block: single 16B load.
  // fwd: stbuf[k][h]. bwd h=0: stbuf[m][0]; bwd h=1: stbuf[m-1][1] (m=750-k).
  int m = PBLK - k;
  int sb_blk = du ? (hu ? (m - 1) : m) : k;
  int s = (iu * 8 + du * 4 + b) * 64 + ch;
  double2 v0 =
      ((const double2*)stbuf)[(size_t)((sb_blk - K0) * 2 + hu) * 1024 + s];
  float st0 = (float)v0.x, st1 = (float)v0.y;

  // W fragments for this wave's single M-tile (rows gu*16..gu*16+15)
  half8 wf[4];
  #pragma unroll
  for (int k0 = 0; k0 < 4; ++k0) {
    const float* wp = W + (gu * 16 + lm) * 128 + k0 * 32 + quad * 8;
    float4 wa = *(const float4*)wp, wb = *(const float4*)(wp + 4);
    half8 h;
    h[0] = (_Float16)wa.x; h[1] = (_Float16)wa.y;
    h[2] = (_Float16)wa.z; h[3] = (_Float16)wa.w;
    h[4] = (_Float16)wb.x; h[5] = (_Float16)wb.y;
    h[6] = (_Float16)wb.z; h[7] = (_Float16)wb.w;
    wf[k0] = h;
  }

  // wave-uniform x pointer -> scalar loads
  const float* xp = (iu ? tgt : pred) + b * T_LEN + k * LBLK + hu * HBLK;

  float loss = 0.0f;
  for (int cc = 0; cc < NCHUNK; ++cc) {
    _Float16* yb = ys[cc & 1];
    // ---- recurrence phase (f32, uniform direction, 16 steps) ----
    if (du == 0) {
      #pragma unroll
      for (int tt = 0; tt < CCH; ++tt) {
        float x = xp[cc * CCH + tt];
        float y = fmaf(-A1, st0, fmaf(-A2, st1, B0 * x));
        yb[(iu + 2 * tt) * YSTR + ch] = (_Float16)y;
        st1 = st0; st0 = y;
      }
    } else {
      #pragma unroll
      for (int tt = 0; tt < CCH; ++tt) {
        float x = xp[cc * CCH + tt];
        yb[(iu + 2 * tt) * YSTR + 64 + ch] = (_Float16)st0;
        float ym2 = (fmaf(-A1, st1, B0 * x) - st0) * IA2;
        st0 = st1; st1 = ym2;
      }
    }
    __syncthreads();   // writes(buf) -> reads(buf); next writes hit other buf

    // ---- MFMA phase: wave computes z[gu*16..+16)[2 col-tiles of 16] ----
    #pragma unroll 1   // keep bf live-range short: stay under 64 VGPRs
    for (int ct = 0; ct < 2; ++ct) {
      const _Float16* yrow = &yb[(ct * 16 + lm) * YSTR + quad * 8];
      half8 bf0 = *(const half8*)(yrow);
      half8 bf1 = *(const half8*)(yrow + 32);
      half8 bf2 = *(const half8*)(yrow + 64);
      half8 bf3 = *(const half8*)(yrow + 96);
      f32x4 c = {0.f, 0.f, 0.f, 0.f};
      c = __builtin_amdgcn_mfma_f32_16x16x32_f16(wf[0], bf0, c, 0, 0, 0);
      c = __builtin_amdgcn_mfma_f32_16x16x32_f16(wf[1], bf1, c, 0, 0, 0);
      c = __builtin_amdgcn_mfma_f32_16x16x32_f16(wf[2], bf2, c, 0, 0, 0);
      c = __builtin_amdgcn_mfma_f32_16x16x32_f16(wf[3], bf3, c, 0, 0, 0);
      #pragma unroll
      for (int r = 0; r < 4; ++r) {
        float vv = fast_tanh(c[r]);
        float p = __shfl_xor(vv, 1);   // partner col = other input, same t
        loss += fabsf(vv - p);
      }
    }
  }

  // block reduction -> one double atomic per workgroup; last wg finalizes
  #pragma unroll
  for (int off = 32; off > 0; off >>= 1) loss += __shfl_down(loss, off);
  if (lane == 0) red[g] = loss;
  __syncthreads();
  if (tid == 0) {
    float blk = (red[0] + red[1]) + (red[2] + red[3]);
    atomicAdd(wsum, (double)blk);
    __threadfence();
    unsigned int n = atomicAdd((unsigned int*)(wsum + 1), 1u);
    if (n == (unsigned int)(NKV * 2 * BATCH - 1)) {
      __threadfence();
      double tot = atomicAdd(wsum, 0.0);   // coherent read of final total
      out[0] = (float)(tot / DENOM);
    }
  }
}

extern "C" void kernel_launch(void* const* d_in, const int* in_sizes, int n_in,
                              void* d_out, int out_size, void* d_ws, size_t ws_size,
                              hipStream_t stream) {
  const float* pred = (const float*)d_in[0];
  const float* tgt  = (const float*)d_in[1];
  const void* a1p = d_in[2];
  const void* a2p = d_in[3];
  const void* b0p = d_in[4];
  const float* W  = (const float*)d_in[5];
  float* out = (float*)d_out;

  double* base = (double*)d_ws;
  double* wsum = base;                              // wsum + u32 counter (8 dbl pad)
  double* fbuf = base + 8;                          // [500][1024][2]
  double* fmid = fbuf + (size_t)PB_USED * 1024 * 2; // [250][1024][2]
  double* sbuf = fmid + (size_t)NKV * 1024 * 2;     // [20][1024][2] (alloc 32)
  double* tbuf = sbuf + (size_t)32 * 1024 * 2;      // [21][1024][2] (alloc 32)
  double* stbuf = tbuf + (size_t)32 * 1024 * 2;     // [251][2][1024][2]

  pass1<<<dim3(PB_USED, 16), 64, 0, stream>>>(pred, tgt, a1p, a2p, b0p,
                                              fbuf, fmid, wsum);
  pass2a<<<NSEG_USED * 16, 64, 0, stream>>>(a1p, a2p, fbuf, sbuf);
  pass2b<<<dim3(4), 256, 0, stream>>>(a1p, a2p, sbuf, tbuf);
  pass2c<<<NSEGC * 16, 64, 0, stream>>>(a1p, a2p, fbuf, fmid, tbuf, stbuf);
  pass3<<<dim3(NKV * 2, BATCH), 256, 0, stream>>>(pred, tgt, a1p, a2p, b0p,
                                                  W, stbuf, wsum, out);
}

// Round 4
// 126.855 us; speedup vs baseline: 1.2599x; 1.2599x over previous
//
#include <hip/hip_runtime.h>

#define T_LEN 120000
#define LBLK 160          // samples per scan block
#define PBLK 750          // logical blocks over T (time geometry)
#define PB_USED 500       // blocks computed (only 0..499 are consumed)
#define SEG_LEN 25        // blocks per scan segment
#define NSEG_USED 20      // segment aggregates needed (blocks 0..499)
#define CCH 32            // t-steps per recurrence wave per chunk
#define NCHUNK 5          // chunks per block (5*32 = 160)
#define BATCH 4
#define K0 250            // first valid block (t = 40000)
#define NKV 250           // valid blocks (t in [40000, 80000))
#define DENOM 20480000.0  // 2 * 4 * 64 * 40000 (each |diff| counted twice)
#define YSTR 130          // halves per ys row: 128 ch + 2 pad (odd dword stride)

typedef _Float16 half8 __attribute__((ext_vector_type(8)));
typedef float f32x4 __attribute__((ext_vector_type(4)));

__device__ __forceinline__ float fast_tanh(float x) {
  float e = __expf(2.0f * x);
  return 1.0f - 2.0f / (e + 1.0f);
}

// Harness may store the reference's float64 coeff arrays as f64 or f32.
// Detect via a2[0] = r^2 in (0.9,1.0). Data-stable -> graph-safe; no OOB.
__device__ __forceinline__ bool coeffs_are_f64(const void* a2p) {
  double probe = *(const double*)a2p;
  return probe > 0.9 && probe < 1.0;
}
__device__ __forceinline__ double coeff_d(const void* p, bool f64, int ch) {
  return f64 ? ((const double*)p)[ch] : (double)((const float*)p)[ch];
}

// state-transition matrix A^e for A = [[-a1,-a2],[1,0]] by repeated squaring
__device__ __forceinline__ void mat_pow(double A1, double A2, int e,
                                        double& r00, double& r01,
                                        double& r10, double& r11) {
  double m00 = -A1, m01 = -A2, m10 = 1.0, m11 = 0.0;
  r00 = 1.0; r01 = 0.0; r10 = 0.0; r11 = 1.0;
  while (e) {
    if (e & 1) {
      double t00 = r00 * m00 + r01 * m10, t01 = r00 * m01 + r01 * m11;
      double t10 = r10 * m00 + r11 * m10, t11 = r10 * m01 + r11 * m11;
      r00 = t00; r01 = t01; r10 = t10; r11 = t11;
    }
    e >>= 1;
    if (e) {
      double t00 = m00 * m00 + m01 * m10, t01 = m00 * m01 + m01 * m11;
      double t10 = m10 * m00 + m11 * m10, t11 = m10 * m01 + m11 * m11;
      m00 = t00; m01 = t01; m10 = t10; m11 = t11;
    }
  }
}

// Pass 1: per (row, block) forced response with zero initial state, f32.
// rows r: r = i*8 + d*4 + b. Also zeroes wsum/counter (block 0 only).
__global__ __launch_bounds__(64) void pass1(
    const float* __restrict__ pred, const float* __restrict__ tgt,
    const void* a1p, const void* a2p, const void* b0p,
    double* __restrict__ fbuf, double* __restrict__ wsum)
{
  if ((blockIdx.x | blockIdx.y) == 0 && threadIdx.x == 0) {
    wsum[0] = 0.0;
    ((unsigned int*)(wsum + 1))[0] = 0u;   // workgroup-done counter
  }
  int k = blockIdx.x, r = blockIdx.y;
  int i = r >> 3, d = (r >> 2) & 1, b = r & 3;
  const float* sig = (i ? tgt : pred) + b * T_LEN;
  __shared__ float xs[LBLK];
  int base = k * LBLK;
  for (int j = threadIdx.x; j < LBLK; j += 64)
    xs[j] = d ? sig[T_LEN - 1 - (base + j)] : sig[base + j];
  __syncthreads();
  int ch = threadIdx.x;
  bool f64 = coeffs_are_f64(a2p);
  float A1 = (float)coeff_d(a1p, f64, ch);
  float A2 = (float)coeff_d(a2p, f64, ch);
  float B0 = (float)coeff_d(b0p, f64, ch);
  float y1 = 0.0f, y2 = 0.0f;
  for (int j = 0; j < LBLK; ++j) {
    float y = fmaf(-A1, y1, fmaf(-A2, y2, B0 * xs[j]));
    y2 = y1; y1 = y;
  }
  int s = r * 64 + ch;
  ((double2*)fbuf)[(size_t)k * 1024 + s] = make_double2((double)y1, (double)y2);
}

// Pass 2a: per-segment aggregate (forced response of 25 blocks, zero init), f64.
__global__ __launch_bounds__(64) void pass2a(
    const void* a1p, const void* a2p,
    const double* __restrict__ fbuf, double* __restrict__ sbuf)
{
  int seg = blockIdx.x >> 4;
  int s = ((blockIdx.x & 15) << 6) + threadIdx.x;
  int ch = s & 63;
  bool f64 = coeffs_are_f64(a2p);
  double r00, r01, r10, r11;
  mat_pow(coeff_d(a1p, f64, ch), coeff_d(a2p, f64, ch), LBLK, r00, r01, r10, r11);
  const double2* fb = (const double2*)fbuf;
  double y1 = 0.0, y2 = 0.0;
  for (int jj = 0; jj < SEG_LEN / 5; ++jj) {
    size_t kb = (size_t)(seg * SEG_LEN + jj * 5) * 1024 + s;
    double2 f0 = fb[kb], f1 = fb[kb + 1024], f2 = fb[kb + 2048],
            f3 = fb[kb + 3072], f4 = fb[kb + 4096];
    double n1, n2;
    n1 = r00*y1 + r01*y2 + f0.x; n2 = r10*y1 + r11*y2 + f0.y; y1=n1; y2=n2;
    n1 = r00*y1 + r01*y2 + f1.x; n2 = r10*y1 + r11*y2 + f1.y; y1=n1; y2=n2;
    n1 = r00*y1 + r01*y2 + f2.x; n2 = r10*y1 + r11*y2 + f2.y; y1=n1; y2=n2;
    n1 = r00*y1 + r01*y2 + f3.x; n2 = r10*y1 + r11*y2 + f3.y; y1=n1; y2=n2;
    n1 = r00*y1 + r01*y2 + f4.x; n2 = r10*y1 + r11*y2 + f4.y; y1=n1; y2=n2;
  }
  ((double2*)sbuf)[(size_t)seg * 1024 + s] = make_double2(y1, y2);
}

// Pass 3: per (valid block k, batch b). Round-0-verified core. Prologue now
// also folds the old pass2b: each wave scans the 20 sbuf segment aggregates
// with A^4000 (uniform predicate, 320B of L2-hot reads) to build its
// segment-start state, then <=24 predicated f64 fbuf steps with A^160.
// Then f32 in-block recurrence -> f16 Y in LDS (double-buffered) -> MFMA
// 16x16x32_f16 -> tanh -> |p-t| reduce. Finalize fused via atomic counter.
__global__ __launch_bounds__(256, 4) void pass3(
    const float* __restrict__ pred, const float* __restrict__ tgt,
    const void* a1p, const void* a2p, const void* b0p,
    const float* __restrict__ W, const double* __restrict__ fbuf,
    const double* __restrict__ sbuf, double* __restrict__ wsum,
    float* __restrict__ out)
{
  int k = K0 + blockIdx.x;
  int b = blockIdx.y;
  int tid = threadIdx.x;
  __shared__ __align__(16) _Float16 ys[2][64 * YSTR]; // [buf][col(2t+i)][128ch]
  __shared__ float red[4];

  int g = tid >> 6, lane = tid & 63;
  int gu = __builtin_amdgcn_readfirstlane(g);   // wave-uniform wave id
  int iu = gu >> 1, du = gu & 1;                // uniform input / direction
  int ch = lane;
  int n0 = gu * 16;                 // wave's N-tile (16 cols = 8 t x 2 inputs)
  int lm = lane & 15, quad = lane >> 4;

  bool f64 = coeffs_are_f64(a2p);
  double A1d = coeff_d(a1p, f64, ch), A2d = coeff_d(a2p, f64, ch);
  double B0d = coeff_d(b0p, f64, ch);
  float A1 = (float)A1d, A2 = (float)A2d, B0 = (float)B0d;
  float IA2 = (float)(1.0 / A2d);

  // ---- prologue: exact f64 state for this wave's scan block ----
  int m = du ? (PBLK - k) : k;            // fwd: block k; bwd: block 750-k
  int seg = m / SEG_LEN, j = m - seg * SEG_LEN;   // wave-uniform; seg in [10,20]
  int s = (iu * 8 + du * 4 + b) * 64 + ch;

  // segment prefix from sbuf aggregates (folded pass2b), A^4000 steps
  double q00, q01, q10, q11;
  mat_pow(A1d, A2d, LBLK * SEG_LEN, q00, q01, q10, q11);
  double y1 = 0.0, y2 = 0.0;
  const double2* sb = (const double2*)sbuf;
  #pragma unroll 1
  for (int qq = 0; qq < NSEG_USED; qq += 5) {
    double2 f[5];
    #pragma unroll
    for (int p = 0; p < 5; ++p) f[p] = sb[(size_t)(qq + p) * 1024 + s];
    #pragma unroll
    for (int p = 0; p < 5; ++p) {
      if (qq + p < seg) {                 // uniform predicate
        double n1 = q00 * y1 + q01 * y2 + f[p].x;
        double n2 = q10 * y1 + q11 * y2 + f[p].y;
        y1 = n1; y2 = n2;
      }
    }
  }

  // block steps within the segment: <=24 predicated A^160 steps over fbuf
  double r00, r01, r10, r11;
  mat_pow(A1d, A2d, LBLK, r00, r01, r10, r11);
  const double2* fb = (const double2*)fbuf;
  #pragma unroll 1
  for (int bb = 0; bb < 24; bb += 8) {
    double2 f[8];
    #pragma unroll
    for (int q = 0; q < 8; ++q) {
      int blk = seg * SEG_LEN + bb + q;
      if (blk >= PB_USED) blk = PB_USED - 1;  // clamp: value unused (q >= j)
      f[q] = fb[(size_t)blk * 1024 + s];
    }
    #pragma unroll
    for (int q = 0; q < 8; ++q) {
      if (bb + q < j) {     // uniform predicate
        double n1 = r00 * y1 + r01 * y2 + f[q].x;
        double n2 = r10 * y1 + r11 * y2 + f[q].y;
        y1 = n1; y2 = n2;
      }
    }
  }
  float st0 = (float)y1, st1 = (float)y2;

  // ---- W fragments: convert f32 -> f16 in registers (wave's 16-row slices) ----
  half8 wf[4][4];
  #pragma unroll
  for (int m0 = 0; m0 < 4; ++m0) {
    #pragma unroll
    for (int k0 = 0; k0 < 4; ++k0) {
      const float* wp = W + (m0 * 16 + lm) * 128 + k0 * 32 + quad * 8;
      float4 wa = *(const float4*)wp, wb = *(const float4*)(wp + 4);
      half8 h;
      h[0] = (_Float16)wa.x; h[1] = (_Float16)wa.y;
      h[2] = (_Float16)wa.z; h[3] = (_Float16)wa.w;
      h[4] = (_Float16)wb.x; h[5] = (_Float16)wb.y;
      h[6] = (_Float16)wb.z; h[7] = (_Float16)wb.w;
      wf[m0][k0] = h;
    }
  }

  // wave-uniform x pointer -> scalar loads
  const float* xp = (iu ? tgt : pred) + b * T_LEN + k * LBLK;

  float loss = 0.0f;
  for (int cc = 0; cc < NCHUNK; ++cc) {
    _Float16* yb = ys[cc & 1];
    // ---- recurrence phase (f32, uniform direction, scalar x) ----
    if (du == 0) {
      #pragma unroll
      for (int tt = 0; tt < CCH; ++tt) {
        float x = xp[cc * CCH + tt];
        float y = fmaf(-A1, st0, fmaf(-A2, st1, B0 * x));
        yb[(2 * tt + iu) * YSTR + ch] = (_Float16)y;
        st1 = st0; st0 = y;
      }
    } else {
      #pragma unroll
      for (int tt = 0; tt < CCH; ++tt) {
        float x = xp[cc * CCH + tt];
        yb[(2 * tt + iu) * YSTR + 64 + ch] = (_Float16)st0;
        float ym2 = (fmaf(-A1, st1, B0 * x) - st0) * IA2;
        st0 = st1; st1 = ym2;
      }
    }
    __syncthreads();   // writes(buf) -> reads(buf); next writes hit other buf

    // ---- MFMA phase: wave computes z[0..63][its 16 cols] ----
    const _Float16* yrow = &yb[(n0 + lm) * YSTR + quad * 8];
    half8 bf0 = *(const half8*)(yrow);
    half8 bf1 = *(const half8*)(yrow + 32);
    half8 bf2 = *(const half8*)(yrow + 64);
    half8 bf3 = *(const half8*)(yrow + 96);
    #pragma unroll
    for (int m0 = 0; m0 < 4; ++m0) {
      f32x4 c = {0.f, 0.f, 0.f, 0.f};
      c = __builtin_amdgcn_mfma_f32_16x16x32_f16(wf[m0][0], bf0, c, 0, 0, 0);
      c = __builtin_amdgcn_mfma_f32_16x16x32_f16(wf[m0][1], bf1, c, 0, 0, 0);
      c = __builtin_amdgcn_mfma_f32_16x16x32_f16(wf[m0][2], bf2, c, 0, 0, 0);
      c = __builtin_amdgcn_mfma_f32_16x16x32_f16(wf[m0][3], bf3, c, 0, 0, 0);
      #pragma unroll
      for (int r = 0; r < 4; ++r) {
        float vv = fast_tanh(c[r]);
        float p = __shfl_xor(vv, 1);   // partner col = other input, same t
        loss += fabsf(vv - p);
      }
    }
  }

  // block reduction -> one double atomic per workgroup; last WG finalizes
  #pragma unroll
  for (int off = 32; off > 0; off >>= 1) loss += __shfl_down(loss, off);
  if (lane == 0) red[g] = loss;
  __syncthreads();
  if (tid == 0) {
    float blk = (red[0] + red[1]) + (red[2] + red[3]);
    atomicAdd(wsum, (double)blk);
    __threadfence();
    unsigned int n = atomicAdd((unsigned int*)(wsum + 1), 1u);
    if (n == (unsigned int)(NKV * BATCH - 1)) {
      __threadfence();
      double tot = atomicAdd(wsum, 0.0);   // coherent read of final total
      out[0] = (float)(tot / DENOM);
    }
  }
}

extern "C" void kernel_launch(void* const* d_in, const int* in_sizes, int n_in,
                              void* d_out, int out_size, void* d_ws, size_t ws_size,
                              hipStream_t stream) {
  const float* pred = (const float*)d_in[0];
  const float* tgt  = (const float*)d_in[1];
  const void* a1p = d_in[2];
  const void* a2p = d_in[3];
  const void* b0p = d_in[4];
  const float* W  = (const float*)d_in[5];
  float* out = (float*)d_out;

  double* base = (double*)d_ws;
  double* wsum = base;                              // wsum + u32 counter (8 dbl pad)
  double* fbuf = base + 8;                          // [500][1024][2]
  double* sbuf = fbuf + (size_t)PB_USED * 1024 * 2; // [20][1024][2]

  pass1<<<dim3(PB_USED, 16), 64, 0, stream>>>(pred, tgt, a1p, a2p, b0p,
                                              fbuf, wsum);
  pass2a<<<NSEG_USED * 16, 64, 0, stream>>>(a1p, a2p, fbuf, sbuf);
  pass3<<<dim3(NKV, BATCH), 256, 0, stream>>>(pred, tgt, a1p, a2p, b0p,
                                              W, fbuf, sbuf, wsum, out);
}